// Round 1
// baseline (614.954 us; speedup 1.0000x reference)
//
#include <hip/hip_runtime.h>
#include <hip/hip_bf16.h>

// A=8, B=32768, S=128, AD=16, H=64, NH=4, D=16
#define A_N 8
#define B_N 32768
#define S_N 128
#define AD_N 16

typedef __attribute__((ext_vector_type(8))) short short8;
typedef __attribute__((ext_vector_type(4))) float floatx4;
typedef __attribute__((ext_vector_type(4))) int intx4;

#define MFMA16(a, b, c) __builtin_amdgcn_mfma_f32_16x16x32_bf16(a, b, c, 0, 0, 0)

__device__ __forceinline__ short f2bf(float f) {
    __hip_bfloat16 h = __float2bfloat16(f);
    return *reinterpret_cast<short*>(&h);
}
// pack 2 f32 -> u32 of 2 bf16 (low short = first arg)
__device__ __forceinline__ int pk(float a, float b) {
    __hip_bfloat162 p = __float22bfloat162_rn(make_float2(a, b));
    return *reinterpret_cast<int*>(&p);
}
__device__ __forceinline__ short8 mk8(int a, int b, int c, int d) {
    intx4 v = {a, b, c, d};
    return *reinterpret_cast<short8*>(&v);
}
__device__ __forceinline__ void pk2(short8& r, int i, float a, float b) {
    __hip_bfloat162 p = __float22bfloat162_rn(make_float2(a, b));
    short2 s = *reinterpret_cast<short2*>(&p);
    r[i] = s.x; r[i + 1] = s.y;
}
__device__ __forceinline__ short8 cvt8(float4 x0, float4 x1) {
    short8 r;
    pk2(r, 0, x0.x, x0.y); pk2(r, 2, x0.z, x0.w);
    pk2(r, 4, x1.x, x1.y); pk2(r, 6, x1.z, x1.w);
    return r;
}

// k-permutation for the phase-2/4 weight operands: physical LDS position p
// (p = s*32 + lq*8 + t) holds logical channel ch = 32s + 16(t>>2) + 4lq + (t&3).
// This makes the activation-side fragment a pure within-lane repack of the
// previous MFMA's accumulator (lane (lq,ln) holds channels nt*16+4lq+i).
__device__ __forceinline__ int chperm(int p) {
    return 32 * (p >> 5) + 16 * ((p & 7) >> 2) + 4 * ((p >> 3) & 3) + (p & 3);
}

// ---- weight prep into d_ws: bf16 [n][k] rows, bank-spread strides ----
// shorts: lWe[64][168]@0 (identity k; k=144 holds be) | lWs[64][168]@10752 (k=144 holds bs)
//         lWk[64][72]@21504 | lWsel[64][72]@26112 | lWv[64][72]@30720 (chperm k)
//         lW1[64][136]@35328 (chperm k)
#define OFF_Ws   10752
#define OFF_Wk   21504
#define OFF_Wsel 26112
#define OFF_Wv   30720
#define OFF_W1   35328
#define W_TOTAL  44032   // shorts = 88064 B = 86 x 1 KiB chunks

__global__ void prep_weights(const float* __restrict__ Ws, const float* __restrict__ bs,
                             const float* __restrict__ We, const float* __restrict__ be,
                             const float* __restrict__ Wk, const float* __restrict__ Wsel,
                             const float* __restrict__ Wv, const float* __restrict__ W1,
                             short* __restrict__ w) {
    int idx = blockIdx.x * 256 + threadIdx.x;
    if (idx >= W_TOTAL) return;
    float v = 0.f;
    if (idx < OFF_Ws) {
        int n = idx / 168, p = idx % 168;
        v = (p < 144) ? We[p * 64 + n] : (p == 144 ? be[n] : 0.f);
    } else if (idx < OFF_Wk) {
        int i = idx - OFF_Ws; int n = i / 168, p = i % 168;
        v = (p < 128) ? Ws[p * 64 + n] : (p == 144 ? bs[n] : 0.f);
    } else if (idx < OFF_Wsel) {
        int i = idx - OFF_Wk; int n = i / 72, p = i % 72;
        if (p < 64) v = Wk[(n >> 4) * 1024 + chperm(p) * 16 + (n & 15)];
    } else if (idx < OFF_Wv) {
        int i = idx - OFF_Wsel; int n = i / 72, p = i % 72;
        if (p < 64) v = Wsel[(n >> 4) * 1024 + chperm(p) * 16 + (n & 15)];
    } else if (idx < OFF_W1) {
        int i = idx - OFF_Wv; int n = i / 72, p = i % 72;
        if (p < 64) v = Wv[(n >> 4) * 1024 + chperm(p) * 16 + (n & 15)];
    } else {
        int i = idx - OFF_W1; int n = i / 136, p = i % 136;
        if (p < 128) v = W1[chperm(p) * 64 + n];
    }
    w[idx] = f2bf(v);
}

#define TILES 4   // 32 batches/tile/block, 128 batches/block, grid = 256 = #CUs

// Register-resident pipeline: all GEMMs operand-swapped so that every
// inter-phase handoff is a within-lane cvt_pk repack (weights carry the k
// permutation). LDS = weights only (88 KB) -> 16 waves/CU (4/SIMD). No LDS
// writes, no barriers, no lgkm turnarounds inside the tile loop.
// Wave wv owns 16 slots = 2 batches x 8 agents; slot s: a=s&7, bl=s>>3.
__global__ __launch_bounds__(1024, 4)
void attention_critic_mfma(
    const float* __restrict__ states, const float* __restrict__ actions,
    const float* __restrict__ bv, const float* __restrict__ b1,
    const float* __restrict__ W2, const float* __restrict__ b2,
    const short* __restrict__ wts, float* __restrict__ out)
{
    __shared__ __align__(16) short smem[W_TOTAL];
    const short* lWe   = smem;
    const short* lWs   = smem + OFF_Ws;
    const short* lWk   = smem + OFF_Wk;
    const short* lWsel = smem + OFF_Wsel;
    const short* lWv   = smem + OFF_Wv;
    const short* lW1   = smem + OFF_W1;

    const int tid  = threadIdx.x;
    const int wv   = tid >> 6;       // wave 0..15
    const int lane = tid & 63;
    const int lq   = lane >> 4;
    const int ln   = lane & 15;

    // ---- stage all weights into LDS (86 x 1KiB chunks, global_load_lds w=16) ----
    for (int c = wv; c < 86; c += 16) {
        const unsigned int* g = reinterpret_cast<const unsigned int*>(wts + c * 512) + lane * 4;
        __builtin_amdgcn_global_load_lds(g, reinterpret_cast<unsigned int*>(smem + c * 512), 16, 0, 0);
    }

    // per-lane bias / head-weight constants (cols of the respective C-layouts)
    float bv4[4], b14[4], w24[4];
    #pragma unroll
    for (int nt = 0; nt < 4; ++nt) {
        bv4[nt] = bv[nt * 16 + ln];
        b14[nt] = b1[nt * 16 + ln];
        w24[nt] = W2[nt * 16 + ln];
    }
    const float b2v = b2[0];

    const int bbase = blockIdx.x * (TILES * 32);
    const int aA  = ln & 7;
    const int blA = ln >> 3;
    const float* srow = states  + ((long)aA * B_N + bbase + wv * 2 + blA) * S_N;
    const float* arow = actions + ((long)aA * B_N + bbase + wv * 2 + blA) * AD_N;

    // prologue: prefetch tile 0 inputs (lane (lq,ln): slot ln, input dims lq*8..)
    float4 ps[8]; float4 pa[2];
    #pragma unroll
    for (int s = 0; s < 4; ++s) {
        ps[2 * s]     = *reinterpret_cast<const float4*>(srow + s * 32 + lq * 8);
        ps[2 * s + 1] = *reinterpret_cast<const float4*>(srow + s * 32 + lq * 8 + 4);
    }
    if (lq < 2) {
        pa[0] = *reinterpret_cast<const float4*>(arow + lq * 8);
        pa[1] = *reinterpret_cast<const float4*>(arow + lq * 8 + 4);
    }
    __syncthreads();   // weights staged

    const floatx4 z  = {0.f, 0.f, 0.f, 0.f};
    const short8  z8 = {0, 0, 0, 0, 0, 0, 0, 0};

    #pragma unroll 1
    for (int t = 0; t < TILES; ++t) {
        const int b0 = bbase + t * 32;

        // ======== Phase 1 (swapped): E^T = We^T@X^T, S^T = Ws^T@X^T ========
        // A = weight rows (out-ch), B = input frags (col = slot = ln).
        // Bias via k=144: xf[4] element 0 is 1.0 on lq==2 (k==144).
        short8 xf[5];
        #pragma unroll
        for (int s = 0; s < 4; ++s) xf[s] = cvt8(ps[2 * s], ps[2 * s + 1]);
        {
            short8 xt = z8;
            if (lq < 2) xt = cvt8(pa[0], pa[1]);
            else if (lq == 2) xt[0] = (short)0x3F80;   // bf16(1.0) at k=144
            xf[4] = xt;
        }
        floatx4 accE[4] = {z, z, z, z}, accS[4] = {z, z, z, z};
        #pragma unroll
        for (int s = 0; s < 5; ++s) {
            const int kk = s * 32 + lq * 8;
            #pragma unroll
            for (int nt = 0; nt < 4; ++nt) {
                accE[nt] = MFMA16(*reinterpret_cast<const short8*>(lWe + (nt * 16 + ln) * 168 + kk), xf[s], accE[nt]);
                accS[nt] = MFMA16(*reinterpret_cast<const short8*>(lWs + (nt * 16 + ln) * 168 + kk), xf[s], accS[nt]);
            }
        }
        // relu + within-lane repack to operand frags (k-perm matches weight LDS)
        int pE[4][2], pS[4][2];
        #pragma unroll
        for (int nt = 0; nt < 4; ++nt) {
            pE[nt][0] = pk(fmaxf(accE[nt][0], 0.f), fmaxf(accE[nt][1], 0.f));
            pE[nt][1] = pk(fmaxf(accE[nt][2], 0.f), fmaxf(accE[nt][3], 0.f));
            pS[nt][0] = pk(fmaxf(accS[nt][0], 0.f), fmaxf(accS[nt][1], 0.f));
            pS[nt][1] = pk(fmaxf(accS[nt][2], 0.f), fmaxf(accS[nt][3], 0.f));
        }
        short8 fE[2] = { mk8(pE[0][0], pE[0][1], pE[1][0], pE[1][1]),
                         mk8(pE[2][0], pE[2][1], pE[3][0], pE[3][1]) };
        short8 fS[2] = { mk8(pS[0][0], pS[0][1], pS[1][0], pS[1][1]),
                         mk8(pS[2][0], pS[2][1], pS[3][0], pS[3][1]) };

        // ======== Phase 2: K^T = Wk^T@E, Sel^T = Wsel^T@S, V = E@Wv,
        //                   accH = E@W1_top (folded early) ========
        floatx4 accK[4] = {z, z, z, z}, accSl[4] = {z, z, z, z};
        floatx4 accV[4] = {z, z, z, z}, accH[4] = {z, z, z, z};
        #pragma unroll
        for (int s = 0; s < 2; ++s) {
            const int kk = s * 32 + lq * 8;
            #pragma unroll
            for (int nt = 0; nt < 4; ++nt) {
                const int rw = (nt * 16 + ln);
                accK[nt]  = MFMA16(*reinterpret_cast<const short8*>(lWk   + rw * 72 + kk), fE[s], accK[nt]);
                accSl[nt] = MFMA16(*reinterpret_cast<const short8*>(lWsel + rw * 72 + kk), fS[s], accSl[nt]);
                accV[nt]  = MFMA16(fE[s], *reinterpret_cast<const short8*>(lWv + rw * 72  + kk), accV[nt]);
                accH[nt]  = MFMA16(fE[s], *reinterpret_cast<const short8*>(lW1 + rw * 136 + kk), accH[nt]);
            }
        }
        // V bias + relu + pack (C_V: rows=slot in regs, col=(head nt, d=ln))
        int pV[4][2];
        #pragma unroll
        for (int nt = 0; nt < 4; ++nt) {
            pV[nt][0] = pk(fmaxf(accV[nt][0] + bv4[nt], 0.f), fmaxf(accV[nt][1] + bv4[nt], 0.f));
            pV[nt][1] = pk(fmaxf(accV[nt][2] + bv4[nt], 0.f), fmaxf(accV[nt][3] + bv4[nt], 0.f));
        }

        // ======== Phase 3: attention, fully in-register ========
        // L-MFMA (K=32, upper half zero): A = own-slot K (rows=j-slot=ln),
        // B = own-slot Sel (cols=i-slot=ln) -> L[j=4lq+i][i=ln].
        // Softmax over j = 4 regs + shfl_xor(16,32). PV-MFMA: A = V (rows=d=ln),
        // B = P -> other^T[d=4lq+i][slot=ln]. Cross-batch/self masked in P.
        int pO[4][2];
        const bool sameb = ((lq >> 1) == (ln >> 3));
        #pragma unroll
        for (int nt = 0; nt < 4; ++nt) {
            short8 fa = mk8(pk(accK[nt][0],  accK[nt][1]),  pk(accK[nt][2],  accK[nt][3]),  0, 0);
            short8 fb = mk8(pk(accSl[nt][0], accSl[nt][1]), pk(accSl[nt][2], accSl[nt][3]), 0, 0);
            floatx4 L = MFMA16(fa, fb, z);
            float lg[4];
            #pragma unroll
            for (int i = 0; i < 4; ++i) {
                const bool valid = sameb && (4 * lq + i != ln);
                lg[i] = valid ? L[i] * 0.25f : -1e9f;   // 1/sqrt(16), exclude self/x-batch
            }
            float m = fmaxf(fmaxf(lg[0], lg[1]), fmaxf(lg[2], lg[3]));
            m = fmaxf(m, __shfl_xor(m, 16, 64));
            m = fmaxf(m, __shfl_xor(m, 32, 64));
            float e0 = __expf(lg[0] - m), e1 = __expf(lg[1] - m);
            float e2 = __expf(lg[2] - m), e3 = __expf(lg[3] - m);
            float ss = e0 + e1 + e2 + e3;
            ss += __shfl_xor(ss, 16, 64);
            ss += __shfl_xor(ss, 32, 64);
            const float inv = 1.f / ss;
            short8 fp = mk8(pk(e0 * inv, e1 * inv), pk(e2 * inv, e3 * inv), 0, 0);
            short8 fv = mk8(pV[nt][0], pV[nt][1], 0, 0);
            floatx4 O = MFMA16(fv, fp, z);
            pO[nt][0] = pk(O[0], O[1]);
            pO[nt][1] = pk(O[2], O[3]);
        }

        // prefetch next tile inputs here (accK/accSl/accV dead; peak VGPR low)
        if (t + 1 < TILES) {
            srow += 32 * S_N; arow += 32 * AD_N;
            #pragma unroll
            for (int s = 0; s < 4; ++s) {
                ps[2 * s]     = *reinterpret_cast<const float4*>(srow + s * 32 + lq * 8);
                ps[2 * s + 1] = *reinterpret_cast<const float4*>(srow + s * 32 + lq * 8 + 4);
            }
            if (lq < 2) {
                pa[0] = *reinterpret_cast<const float4*>(arow + lq * 8);
                pa[1] = *reinterpret_cast<const float4*>(arow + lq * 8 + 4);
            }
        }

        // ======== Phase 4: accH += other @ W1_bot ; q = relu(h)@W2 + b2 ========
        short8 fO[2] = { mk8(pO[0][0], pO[0][1], pO[1][0], pO[1][1]),
                         mk8(pO[2][0], pO[2][1], pO[3][0], pO[3][1]) };
        #pragma unroll
        for (int s = 2; s < 4; ++s) {
            const int kk = s * 32 + lq * 8;
            #pragma unroll
            for (int nt = 0; nt < 4; ++nt)
                accH[nt] = MFMA16(fO[s - 2], *reinterpret_cast<const short8*>(lW1 + (nt * 16 + ln) * 136 + kk), accH[nt]);
        }
        float p0 = 0.f, p1 = 0.f, p2 = 0.f, p3 = 0.f;
        #pragma unroll
        for (int nt = 0; nt < 4; ++nt) {
            p0 += fmaxf(accH[nt][0] + b14[nt], 0.f) * w24[nt];
            p1 += fmaxf(accH[nt][1] + b14[nt], 0.f) * w24[nt];
            p2 += fmaxf(accH[nt][2] + b14[nt], 0.f) * w24[nt];
            p3 += fmaxf(accH[nt][3] + b14[nt], 0.f) * w24[nt];
        }
        #pragma unroll
        for (int mk = 1; mk < 16; mk <<= 1) {
            p0 += __shfl_xor(p0, mk, 64);
            p1 += __shfl_xor(p1, mk, 64);
            p2 += __shfl_xor(p2, mk, 64);
            p3 += __shfl_xor(p3, mk, 64);
        }
        if (ln == 0) {
            float pr[4] = {p0, p1, p2, p3};
            #pragma unroll
            for (int i = 0; i < 4; ++i) {
                const int slot = lq * 4 + i;           // slot -> (a = slot&7, bl = slot>>3)
                out[(long)(slot & 7) * B_N + b0 + wv * 2 + (slot >> 3)] = pr[i] + b2v;
            }
        }
        // no barriers: everything wave/lane-local; waves free-run across tiles
    }
}

extern "C" void kernel_launch(void* const* d_in, const int* in_sizes, int n_in,
                              void* d_out, int out_size, void* d_ws, size_t ws_size,
                              hipStream_t stream) {
    const float* states  = (const float*)d_in[0];
    const float* actions = (const float*)d_in[1];
    const float* Ws      = (const float*)d_in[2];
    const float* bs      = (const float*)d_in[3];
    const float* We      = (const float*)d_in[4];
    const float* be      = (const float*)d_in[5];
    const float* Wk      = (const float*)d_in[6];
    const float* Wsel    = (const float*)d_in[7];
    const float* Wv      = (const float*)d_in[8];
    const float* bv      = (const float*)d_in[9];
    const float* W1      = (const float*)d_in[10];
    const float* b1      = (const float*)d_in[11];
    const float* W2      = (const float*)d_in[12];
    const float* b2      = (const float*)d_in[13];
    short* wts = (short*)d_ws;
    float* out = (float*)d_out;

    prep_weights<<<(W_TOTAL + 255) / 256, 256, 0, stream>>>(Ws, bs, We, be, Wk, Wsel, Wv, W1, wts);
    attention_critic_mfma<<<B_N / (TILES * 32), 1024, 0, stream>>>(
        states, actions, bv, b1, W2, b2, wts, out);
}

// Round 2
// 539.297 us; speedup vs baseline: 1.1403x; 1.1403x over previous
//
#include <hip/hip_runtime.h>
#include <hip/hip_bf16.h>

// A=8, B=32768, S=128, AD=16, H=64, NH=4, D=16
#define A_N 8
#define B_N 32768
#define S_N 128
#define AD_N 16

typedef __attribute__((ext_vector_type(8))) short short8;
typedef __attribute__((ext_vector_type(4))) float floatx4;
typedef __attribute__((ext_vector_type(4))) int intx4;

#define MFMA16(a, b, c) __builtin_amdgcn_mfma_f32_16x16x32_bf16(a, b, c, 0, 0, 0)

__device__ __forceinline__ short f2bf(float f) {
    __hip_bfloat16 h = __float2bfloat16(f);
    return *reinterpret_cast<short*>(&h);
}
// pack 2 f32 -> u32 of 2 bf16 (low short = first arg)
__device__ __forceinline__ int pk(float a, float b) {
    __hip_bfloat162 p = __float22bfloat162_rn(make_float2(a, b));
    return *reinterpret_cast<int*>(&p);
}
__device__ __forceinline__ short8 mk8(int a, int b, int c, int d) {
    intx4 v = {a, b, c, d};
    return *reinterpret_cast<short8*>(&v);
}
__device__ __forceinline__ void pk2(short8& r, int i, float a, float b) {
    __hip_bfloat162 p = __float22bfloat162_rn(make_float2(a, b));
    short2 s = *reinterpret_cast<short2*>(&p);
    r[i] = s.x; r[i + 1] = s.y;
}
__device__ __forceinline__ short8 cvt8(float4 x0, float4 x1) {
    short8 r;
    pk2(r, 0, x0.x, x0.y); pk2(r, 2, x0.z, x0.w);
    pk2(r, 4, x1.x, x1.y); pk2(r, 6, x1.z, x1.w);
    return r;
}

// k-permutation for the phase-2/4 weight operands: physical LDS position p
// (p = s*32 + lq*8 + t) holds logical channel ch = 32s + 16(t>>2) + 4lq + (t&3).
// This makes the activation-side fragment a pure within-lane repack of the
// previous MFMA's accumulator (lane (lq,ln) holds channels nt*16+4lq+i).
__device__ __forceinline__ int chperm(int p) {
    return 32 * (p >> 5) + 16 * ((p & 7) >> 2) + 4 * ((p >> 3) & 3) + (p & 3);
}

// ---- weight prep into d_ws: bf16 [n][k] rows, bank-spread strides ----
// shorts: lWe[64][168]@0 (identity k; k=144 holds be) | lWs[64][168]@10752 (k=144 holds bs)
//         lWk[64][72]@21504 | lWsel[64][72]@26112 | lWv[64][72]@30720 (chperm k)
//         lW1[64][136]@35328 (chperm k)
#define OFF_Ws   10752
#define OFF_Wk   21504
#define OFF_Wsel 26112
#define OFF_Wv   30720
#define OFF_W1   35328
#define W_TOTAL  44032   // shorts = 88064 B = 86 x 1 KiB chunks

__global__ void prep_weights(const float* __restrict__ Ws, const float* __restrict__ bs,
                             const float* __restrict__ We, const float* __restrict__ be,
                             const float* __restrict__ Wk, const float* __restrict__ Wsel,
                             const float* __restrict__ Wv, const float* __restrict__ W1,
                             short* __restrict__ w) {
    int idx = blockIdx.x * 256 + threadIdx.x;
    if (idx >= W_TOTAL) return;
    float v = 0.f;
    if (idx < OFF_Ws) {
        int n = idx / 168, p = idx % 168;
        v = (p < 144) ? We[p * 64 + n] : (p == 144 ? be[n] : 0.f);
    } else if (idx < OFF_Wk) {
        int i = idx - OFF_Ws; int n = i / 168, p = i % 168;
        v = (p < 128) ? Ws[p * 64 + n] : (p == 144 ? bs[n] : 0.f);
    } else if (idx < OFF_Wsel) {
        int i = idx - OFF_Wk; int n = i / 72, p = i % 72;
        if (p < 64) v = Wk[(n >> 4) * 1024 + chperm(p) * 16 + (n & 15)];
    } else if (idx < OFF_Wv) {
        int i = idx - OFF_Wsel; int n = i / 72, p = i % 72;
        if (p < 64) v = Wsel[(n >> 4) * 1024 + chperm(p) * 16 + (n & 15)];
    } else if (idx < OFF_W1) {
        int i = idx - OFF_Wv; int n = i / 72, p = i % 72;
        if (p < 64) v = Wv[(n >> 4) * 1024 + chperm(p) * 16 + (n & 15)];
    } else {
        int i = idx - OFF_W1; int n = i / 136, p = i % 136;
        if (p < 128) v = W1[chperm(p) * 64 + n];
    }
    w[idx] = f2bf(v);
}

#define TILES 4   // 32 batches/tile/block, 128 batches/block, grid = 256 = #CUs

// Register-resident pipeline, v2 (spill fix): no f32 prefetch arrays (inputs
// load+convert to bf16 at tile start; memory-bound 8:1 so TLP across 16
// waves/CU hides the latency), and the W1-top fold is deferred to phase 4 so
// accH is never live across phases 2-3. Peak live-set ~90 VGPR < 128 cap.
// Wave wv owns 16 slots = 2 batches x 8 agents; slot s: a=s&7, bl=s>>3.
__global__ __launch_bounds__(1024, 4)
void attention_critic_mfma(
    const float* __restrict__ states, const float* __restrict__ actions,
    const float* __restrict__ bv, const float* __restrict__ b1,
    const float* __restrict__ W2, const float* __restrict__ b2,
    const short* __restrict__ wts, float* __restrict__ out)
{
    __shared__ __align__(16) short smem[W_TOTAL];
    const short* lWe   = smem;
    const short* lWs   = smem + OFF_Ws;
    const short* lWk   = smem + OFF_Wk;
    const short* lWsel = smem + OFF_Wsel;
    const short* lWv   = smem + OFF_Wv;
    const short* lW1   = smem + OFF_W1;

    const int tid  = threadIdx.x;
    const int wv   = tid >> 6;       // wave 0..15
    const int lane = tid & 63;
    const int lq   = lane >> 4;
    const int ln   = lane & 15;

    // ---- stage all weights into LDS (86 x 1KiB chunks, global_load_lds w=16) ----
    for (int c = wv; c < 86; c += 16) {
        const unsigned int* g = reinterpret_cast<const unsigned int*>(wts + c * 512) + lane * 4;
        __builtin_amdgcn_global_load_lds(g, reinterpret_cast<unsigned int*>(smem + c * 512), 16, 0, 0);
    }

    // per-lane bias / head-weight constants (cols of the respective C-layouts)
    float bv4[4], b14[4], w24[4];
    #pragma unroll
    for (int nt = 0; nt < 4; ++nt) {
        bv4[nt] = bv[nt * 16 + ln];
        b14[nt] = b1[nt * 16 + ln];
        w24[nt] = W2[nt * 16 + ln];
    }
    const float b2v = b2[0];

    const int bbase = blockIdx.x * (TILES * 32);
    const int aA  = ln & 7;
    const int blA = ln >> 3;
    const float* srow = states  + ((long)aA * B_N + bbase + wv * 2 + blA) * S_N;
    const float* arow = actions + ((long)aA * B_N + bbase + wv * 2 + blA) * AD_N;

    __syncthreads();   // weights staged (drains vmcnt incl. global_load_lds)

    const floatx4 z  = {0.f, 0.f, 0.f, 0.f};
    const short8  z8 = {0, 0, 0, 0, 0, 0, 0, 0};

    #pragma unroll 1
    for (int t = 0; t < TILES; ++t) {
        const int b0 = bbase + t * 32;

        // ---- load + convert this tile's inputs (transient f32, 20-reg xf) ----
        short8 xf[5];
        #pragma unroll
        for (int s = 0; s < 4; ++s) {
            float4 f0 = *reinterpret_cast<const float4*>(srow + s * 32 + lq * 8);
            float4 f1 = *reinterpret_cast<const float4*>(srow + s * 32 + lq * 8 + 4);
            xf[s] = cvt8(f0, f1);
        }
        {
            short8 xt = z8;
            if (lq < 2) {
                float4 f0 = *reinterpret_cast<const float4*>(arow + lq * 8);
                float4 f1 = *reinterpret_cast<const float4*>(arow + lq * 8 + 4);
                xt = cvt8(f0, f1);
            } else if (lq == 2) {
                xt[0] = (short)0x3F80;   // bf16(1.0) at k=144 -> bias row
            }
            xf[4] = xt;
        }
        srow += 32 * S_N; arow += 32 * AD_N;

        // ======== Phase 1 (swapped): E^T = We^T@X^T, S^T = Ws^T@X^T ========
        floatx4 accE[4] = {z, z, z, z}, accS[4] = {z, z, z, z};
        #pragma unroll
        for (int s = 0; s < 5; ++s) {
            const int kk = s * 32 + lq * 8;
            #pragma unroll
            for (int nt = 0; nt < 4; ++nt) {
                accE[nt] = MFMA16(*reinterpret_cast<const short8*>(lWe + (nt * 16 + ln) * 168 + kk), xf[s], accE[nt]);
                accS[nt] = MFMA16(*reinterpret_cast<const short8*>(lWs + (nt * 16 + ln) * 168 + kk), xf[s], accS[nt]);
            }
        }
        // relu + within-lane repack to operand frags (k-perm matches weight LDS)
        int pE[4][2], pS[4][2];
        #pragma unroll
        for (int nt = 0; nt < 4; ++nt) {
            pE[nt][0] = pk(fmaxf(accE[nt][0], 0.f), fmaxf(accE[nt][1], 0.f));
            pE[nt][1] = pk(fmaxf(accE[nt][2], 0.f), fmaxf(accE[nt][3], 0.f));
            pS[nt][0] = pk(fmaxf(accS[nt][0], 0.f), fmaxf(accS[nt][1], 0.f));
            pS[nt][1] = pk(fmaxf(accS[nt][2], 0.f), fmaxf(accS[nt][3], 0.f));
        }
        short8 fE[2] = { mk8(pE[0][0], pE[0][1], pE[1][0], pE[1][1]),
                         mk8(pE[2][0], pE[2][1], pE[3][0], pE[3][1]) };
        short8 fS[2] = { mk8(pS[0][0], pS[0][1], pS[1][0], pS[1][1]),
                         mk8(pS[2][0], pS[2][1], pS[3][0], pS[3][1]) };

        // ======== Phase 2: K^T = Wk^T@E, Sel^T = Wsel^T@S, V = E@Wv ========
        floatx4 accK[4] = {z, z, z, z}, accSl[4] = {z, z, z, z}, accV[4] = {z, z, z, z};
        #pragma unroll
        for (int s = 0; s < 2; ++s) {
            const int kk = s * 32 + lq * 8;
            #pragma unroll
            for (int nt = 0; nt < 4; ++nt) {
                const int rw = (nt * 16 + ln);
                accK[nt]  = MFMA16(*reinterpret_cast<const short8*>(lWk   + rw * 72 + kk), fE[s], accK[nt]);
                accSl[nt] = MFMA16(*reinterpret_cast<const short8*>(lWsel + rw * 72 + kk), fS[s], accSl[nt]);
                accV[nt]  = MFMA16(fE[s], *reinterpret_cast<const short8*>(lWv + rw * 72 + kk), accV[nt]);
            }
        }
        // V bias + relu + pack (C_V: rows=slot in regs, col=(head nt, d=ln))
        int pV[4][2];
        #pragma unroll
        for (int nt = 0; nt < 4; ++nt) {
            pV[nt][0] = pk(fmaxf(accV[nt][0] + bv4[nt], 0.f), fmaxf(accV[nt][1] + bv4[nt], 0.f));
            pV[nt][1] = pk(fmaxf(accV[nt][2] + bv4[nt], 0.f), fmaxf(accV[nt][3] + bv4[nt], 0.f));
        }

        // ======== Phase 3: attention, fully in-register ========
        // L-MFMA (K=32, upper half zero): A = own-slot K (rows=j-slot=ln),
        // B = own-slot Sel (cols=i-slot=ln) -> L[j=4lq+i][i=ln].
        // Softmax over j = 4 regs + shfl_xor(16,32). PV-MFMA: A = V (rows=d=ln),
        // B = P -> other^T[d=4lq+i][slot=ln]. Cross-batch/self masked in P.
        int pO[4][2];
        const bool sameb = ((lq >> 1) == (ln >> 3));
        #pragma unroll
        for (int nt = 0; nt < 4; ++nt) {
            short8 fa = mk8(pk(accK[nt][0],  accK[nt][1]),  pk(accK[nt][2],  accK[nt][3]),  0, 0);
            short8 fb = mk8(pk(accSl[nt][0], accSl[nt][1]), pk(accSl[nt][2], accSl[nt][3]), 0, 0);
            floatx4 L = MFMA16(fa, fb, z);
            float lg[4];
            #pragma unroll
            for (int i = 0; i < 4; ++i) {
                const bool valid = sameb && (4 * lq + i != ln);
                lg[i] = valid ? L[i] * 0.25f : -1e9f;   // 1/sqrt(16), exclude self/x-batch
            }
            float m = fmaxf(fmaxf(lg[0], lg[1]), fmaxf(lg[2], lg[3]));
            m = fmaxf(m, __shfl_xor(m, 16, 64));
            m = fmaxf(m, __shfl_xor(m, 32, 64));
            float e0 = __expf(lg[0] - m), e1 = __expf(lg[1] - m);
            float e2 = __expf(lg[2] - m), e3 = __expf(lg[3] - m);
            float ss = e0 + e1 + e2 + e3;
            ss += __shfl_xor(ss, 16, 64);
            ss += __shfl_xor(ss, 32, 64);
            const float inv = 1.f / ss;
            short8 fp = mk8(pk(e0 * inv, e1 * inv), pk(e2 * inv, e3 * inv), 0, 0);
            short8 fv = mk8(pV[nt][0], pV[nt][1], 0, 0);
            floatx4 O = MFMA16(fv, fp, z);
            pO[nt][0] = pk(O[0], O[1]);
            pO[nt][1] = pk(O[2], O[3]);
        }

        // ======== Phase 4: h = relu([E|other]@W1+b1) ; q = h@W2 + b2 ========
        short8 fO[2] = { mk8(pO[0][0], pO[0][1], pO[1][0], pO[1][1]),
                         mk8(pO[2][0], pO[2][1], pO[3][0], pO[3][1]) };
        floatx4 accH[4] = {z, z, z, z};
        #pragma unroll
        for (int s = 0; s < 4; ++s) {
            const int kk = s * 32 + lq * 8;
            const short8 af = (s < 2) ? fE[s] : fO[s - 2];
            #pragma unroll
            for (int nt = 0; nt < 4; ++nt)
                accH[nt] = MFMA16(af, *reinterpret_cast<const short8*>(lW1 + (nt * 16 + ln) * 136 + kk), accH[nt]);
        }
        float p0 = 0.f, p1 = 0.f, p2 = 0.f, p3 = 0.f;
        #pragma unroll
        for (int nt = 0; nt < 4; ++nt) {
            p0 += fmaxf(accH[nt][0] + b14[nt], 0.f) * w24[nt];
            p1 += fmaxf(accH[nt][1] + b14[nt], 0.f) * w24[nt];
            p2 += fmaxf(accH[nt][2] + b14[nt], 0.f) * w24[nt];
            p3 += fmaxf(accH[nt][3] + b14[nt], 0.f) * w24[nt];
        }
        #pragma unroll
        for (int mk = 1; mk < 16; mk <<= 1) {
            p0 += __shfl_xor(p0, mk, 64);
            p1 += __shfl_xor(p1, mk, 64);
            p2 += __shfl_xor(p2, mk, 64);
            p3 += __shfl_xor(p3, mk, 64);
        }
        if (ln == 0) {
            float pr[4] = {p0, p1, p2, p3};
            #pragma unroll
            for (int i = 0; i < 4; ++i) {
                const int slot = lq * 4 + i;           // slot -> (a = slot&7, bl = slot>>3)
                out[(long)(slot & 7) * B_N + b0 + wv * 2 + (slot >> 3)] = pr[i] + b2v;
            }
        }
        // no barriers: everything wave/lane-local; waves free-run across tiles
    }
}

extern "C" void kernel_launch(void* const* d_in, const int* in_sizes, int n_in,
                              void* d_out, int out_size, void* d_ws, size_t ws_size,
                              hipStream_t stream) {
    const float* states  = (const float*)d_in[0];
    const float* actions = (const float*)d_in[1];
    const float* Ws      = (const float*)d_in[2];
    const float* bs      = (const float*)d_in[3];
    const float* We      = (const float*)d_in[4];
    const float* be      = (const float*)d_in[5];
    const float* Wk      = (const float*)d_in[6];
    const float* Wsel    = (const float*)d_in[7];
    const float* Wv      = (const float*)d_in[8];
    const float* bv      = (const float*)d_in[9];
    const float* W1      = (const float*)d_in[10];
    const float* b1      = (const float*)d_in[11];
    const float* W2      = (const float*)d_in[12];
    const float* b2      = (const float*)d_in[13];
    short* wts = (short*)d_ws;
    float* out = (float*)d_out;

    prep_weights<<<(W_TOTAL + 255) / 256, 256, 0, stream>>>(Ws, bs, We, be, Wk, Wsel, Wv, W1, wts);
    attention_critic_mfma<<<B_N / (TILES * 32), 1024, 0, stream>>>(
        states, actions, bv, b1, W2, b2, wts, out);
}

// Round 3
// 350.906 us; speedup vs baseline: 1.7525x; 1.5369x over previous
//
#include <hip/hip_runtime.h>
#include <hip/hip_bf16.h>

// A=8, B=32768, S=128, AD=16, H=64, NH=4, D=16
#define A_N 8
#define B_N 32768
#define S_N 128
#define AD_N 16

typedef __attribute__((ext_vector_type(8))) short short8;
typedef __attribute__((ext_vector_type(4))) float floatx4;
typedef __attribute__((ext_vector_type(4))) int intx4;

#define MFMA16(a, b, c) __builtin_amdgcn_mfma_f32_16x16x32_bf16(a, b, c, 0, 0, 0)

__device__ __forceinline__ short f2bf(float f) {
    __hip_bfloat16 h = __float2bfloat16(f);
    return *reinterpret_cast<short*>(&h);
}
// pack 2 f32 -> u32 of 2 bf16 (low short = first arg)
__device__ __forceinline__ int pk(float a, float b) {
    __hip_bfloat162 p = __float22bfloat162_rn(make_float2(a, b));
    return *reinterpret_cast<int*>(&p);
}
__device__ __forceinline__ short8 mk8(int a, int b, int c, int d) {
    intx4 v = {a, b, c, d};
    return *reinterpret_cast<short8*>(&v);
}
__device__ __forceinline__ void pk2(short8& r, int i, float a, float b) {
    __hip_bfloat162 p = __float22bfloat162_rn(make_float2(a, b));
    short2 s = *reinterpret_cast<short2*>(&p);
    r[i] = s.x; r[i + 1] = s.y;
}
__device__ __forceinline__ short8 cvt8(float4 x0, float4 x1) {
    short8 r;
    pk2(r, 0, x0.x, x0.y); pk2(r, 2, x0.z, x0.w);
    pk2(r, 4, x1.x, x1.y); pk2(r, 6, x1.z, x1.w);
    return r;
}

// k-permutation for the phase-2/4 weight operands: physical LDS position p
// (p = s*32 + lq*8 + t) holds logical channel ch = 32s + 16(t>>2) + 4lq + (t&3).
// This makes the activation-side fragment a pure within-lane repack of the
// previous MFMA's accumulator (lane (lq,ln) holds channels nt*16+4lq+i).
__device__ __forceinline__ int chperm(int p) {
    return 32 * (p >> 5) + 16 * ((p & 7) >> 2) + 4 * ((p >> 3) & 3) + (p & 3);
}

// ---- weight prep into d_ws: bf16 [n][k] rows, bank-spread strides ----
// shorts: lWe[64][168]@0 (identity k; k=144 holds be) | lWs[64][168]@10752 (k=144 holds bs)
//         lWk[64][72]@21504 | lWsel[64][72]@26112 | lWv[64][72]@30720 (chperm k)
//         lW1[64][136]@35328 (chperm k)
#define OFF_Ws   10752
#define OFF_Wk   21504
#define OFF_Wsel 26112
#define OFF_Wv   30720
#define OFF_W1   35328
#define W_TOTAL  44032   // shorts = 88064 B = 86 x 1 KiB chunks

__global__ void prep_weights(const float* __restrict__ Ws, const float* __restrict__ bs,
                             const float* __restrict__ We, const float* __restrict__ be,
                             const float* __restrict__ Wk, const float* __restrict__ Wsel,
                             const float* __restrict__ Wv, const float* __restrict__ W1,
                             short* __restrict__ w) {
    int idx = blockIdx.x * 256 + threadIdx.x;
    if (idx >= W_TOTAL) return;
    float v = 0.f;
    if (idx < OFF_Ws) {
        int n = idx / 168, p = idx % 168;
        v = (p < 144) ? We[p * 64 + n] : (p == 144 ? be[n] : 0.f);
    } else if (idx < OFF_Wk) {
        int i = idx - OFF_Ws; int n = i / 168, p = i % 168;
        v = (p < 128) ? Ws[p * 64 + n] : (p == 144 ? bs[n] : 0.f);
    } else if (idx < OFF_Wsel) {
        int i = idx - OFF_Wk; int n = i / 72, p = i % 72;
        if (p < 64) v = Wk[(n >> 4) * 1024 + chperm(p) * 16 + (n & 15)];
    } else if (idx < OFF_Wv) {
        int i = idx - OFF_Wsel; int n = i / 72, p = i % 72;
        if (p < 64) v = Wsel[(n >> 4) * 1024 + chperm(p) * 16 + (n & 15)];
    } else if (idx < OFF_W1) {
        int i = idx - OFF_Wv; int n = i / 72, p = i % 72;
        if (p < 64) v = Wv[(n >> 4) * 1024 + chperm(p) * 16 + (n & 15)];
    } else {
        int i = idx - OFF_W1; int n = i / 136, p = i % 136;
        if (p < 128) v = W1[chperm(p) * 64 + n];
    }
    w[idx] = f2bf(v);
}

#define TILES 8   // 16 batches/tile/block, 128 batches/block, grid = 256 = #CUs

// Register-resident pipeline, v3 (budget fix): 512-thread blocks with
// __launch_bounds__(512,2) -> 8-wave block needs only 2 waves/SIMD residency,
// so the unified VGPR cap is 256/wave (vs 128 at 1024 threads) and the ~150-reg
// live-set fits with NO scratch spill. 8 free-running waves/CU desync across
// the barrier-less tile loop, overlapping one wave's tile loads with the
// others' compute (needed in-flight/CU ~9 KB << 8 waves x 9 KB posted).
// Wave wv owns 16 slots = 2 batches x 8 agents; slot s: a=s&7, bl=s>>3.
__global__ __launch_bounds__(512, 2)
void attention_critic_mfma(
    const float* __restrict__ states, const float* __restrict__ actions,
    const float* __restrict__ bv, const float* __restrict__ b1,
    const float* __restrict__ W2, const float* __restrict__ b2,
    const short* __restrict__ wts, float* __restrict__ out)
{
    __shared__ __align__(16) short smem[W_TOTAL];
    const short* lWe   = smem;
    const short* lWs   = smem + OFF_Ws;
    const short* lWk   = smem + OFF_Wk;
    const short* lWsel = smem + OFF_Wsel;
    const short* lWv   = smem + OFF_Wv;
    const short* lW1   = smem + OFF_W1;

    const int tid  = threadIdx.x;
    const int wv   = tid >> 6;       // wave 0..7
    const int lane = tid & 63;
    const int lq   = lane >> 4;
    const int ln   = lane & 15;

    // ---- stage all weights into LDS (86 x 1KiB chunks, global_load_lds w=16) ----
    for (int c = wv; c < 86; c += 8) {
        const unsigned int* g = reinterpret_cast<const unsigned int*>(wts + c * 512) + lane * 4;
        __builtin_amdgcn_global_load_lds(g, reinterpret_cast<unsigned int*>(smem + c * 512), 16, 0, 0);
    }

    // per-lane bias / head-weight constants (cols of the respective C-layouts)
    float bv4[4], b14[4], w24[4];
    #pragma unroll
    for (int nt = 0; nt < 4; ++nt) {
        bv4[nt] = bv[nt * 16 + ln];
        b14[nt] = b1[nt * 16 + ln];
        w24[nt] = W2[nt * 16 + ln];
    }
    const float b2v = b2[0];

    const int bbase = blockIdx.x * (TILES * 16);
    const int aA  = ln & 7;
    const int blA = ln >> 3;
    const float* srow = states  + ((long)aA * B_N + bbase + wv * 2 + blA) * S_N;
    const float* arow = actions + ((long)aA * B_N + bbase + wv * 2 + blA) * AD_N;

    __syncthreads();   // weights staged (drains vmcnt incl. global_load_lds)

    const floatx4 z  = {0.f, 0.f, 0.f, 0.f};
    const short8  z8 = {0, 0, 0, 0, 0, 0, 0, 0};

    #pragma unroll 1
    for (int t = 0; t < TILES; ++t) {
        const int b0 = bbase + t * 16;

        // ---- load + convert this tile's inputs (transient f32, 20-reg xf) ----
        short8 xf[5];
        #pragma unroll
        for (int s = 0; s < 4; ++s) {
            float4 f0 = *reinterpret_cast<const float4*>(srow + s * 32 + lq * 8);
            float4 f1 = *reinterpret_cast<const float4*>(srow + s * 32 + lq * 8 + 4);
            xf[s] = cvt8(f0, f1);
        }
        {
            short8 xt = z8;
            if (lq < 2) {
                float4 f0 = *reinterpret_cast<const float4*>(arow + lq * 8);
                float4 f1 = *reinterpret_cast<const float4*>(arow + lq * 8 + 4);
                xt = cvt8(f0, f1);
            } else if (lq == 2) {
                xt[0] = (short)0x3F80;   // bf16(1.0) at k=144 -> bias row
            }
            xf[4] = xt;
        }
        srow += 16 * S_N; arow += 16 * AD_N;

        // ======== Phase 1 (swapped): E^T = We^T@X^T, S^T = Ws^T@X^T ========
        floatx4 accE[4] = {z, z, z, z}, accS[4] = {z, z, z, z};
        #pragma unroll
        for (int s = 0; s < 5; ++s) {
            const int kk = s * 32 + lq * 8;
            #pragma unroll
            for (int nt = 0; nt < 4; ++nt) {
                accE[nt] = MFMA16(*reinterpret_cast<const short8*>(lWe + (nt * 16 + ln) * 168 + kk), xf[s], accE[nt]);
                accS[nt] = MFMA16(*reinterpret_cast<const short8*>(lWs + (nt * 16 + ln) * 168 + kk), xf[s], accS[nt]);
            }
        }
        // relu + within-lane repack to operand frags (k-perm matches weight LDS)
        int pE[4][2], pS[4][2];
        #pragma unroll
        for (int nt = 0; nt < 4; ++nt) {
            pE[nt][0] = pk(fmaxf(accE[nt][0], 0.f), fmaxf(accE[nt][1], 0.f));
            pE[nt][1] = pk(fmaxf(accE[nt][2], 0.f), fmaxf(accE[nt][3], 0.f));
            pS[nt][0] = pk(fmaxf(accS[nt][0], 0.f), fmaxf(accS[nt][1], 0.f));
            pS[nt][1] = pk(fmaxf(accS[nt][2], 0.f), fmaxf(accS[nt][3], 0.f));
        }
        short8 fE[2] = { mk8(pE[0][0], pE[0][1], pE[1][0], pE[1][1]),
                         mk8(pE[2][0], pE[2][1], pE[3][0], pE[3][1]) };
        short8 fS[2] = { mk8(pS[0][0], pS[0][1], pS[1][0], pS[1][1]),
                         mk8(pS[2][0], pS[2][1], pS[3][0], pS[3][1]) };

        // ======== Phase 2: K^T = Wk^T@E, Sel^T = Wsel^T@S, V = E@Wv ========
        floatx4 accK[4] = {z, z, z, z}, accSl[4] = {z, z, z, z}, accV[4] = {z, z, z, z};
        #pragma unroll
        for (int s = 0; s < 2; ++s) {
            const int kk = s * 32 + lq * 8;
            #pragma unroll
            for (int nt = 0; nt < 4; ++nt) {
                const int rw = (nt * 16 + ln);
                accK[nt]  = MFMA16(*reinterpret_cast<const short8*>(lWk   + rw * 72 + kk), fE[s], accK[nt]);
                accSl[nt] = MFMA16(*reinterpret_cast<const short8*>(lWsel + rw * 72 + kk), fS[s], accSl[nt]);
                accV[nt]  = MFMA16(fE[s], *reinterpret_cast<const short8*>(lWv + rw * 72 + kk), accV[nt]);
            }
        }
        // V bias + relu + pack (C_V: rows=slot in regs, col=(head nt, d=ln))
        int pV[4][2];
        #pragma unroll
        for (int nt = 0; nt < 4; ++nt) {
            pV[nt][0] = pk(fmaxf(accV[nt][0] + bv4[nt], 0.f), fmaxf(accV[nt][1] + bv4[nt], 0.f));
            pV[nt][1] = pk(fmaxf(accV[nt][2] + bv4[nt], 0.f), fmaxf(accV[nt][3] + bv4[nt], 0.f));
        }

        // ======== Phase 3: attention, fully in-register ========
        // L-MFMA (K=32, upper half zero): A = own-slot K (rows=j-slot=ln),
        // B = own-slot Sel (cols=i-slot=ln) -> L[j=4lq+i][i=ln].
        // Softmax over j = 4 regs + shfl_xor(16,32). PV-MFMA: A = V (rows=d=ln),
        // B = P -> other^T[d=4lq+i][slot=ln]. Cross-batch/self masked in P.
        int pO[4][2];
        const bool sameb = ((lq >> 1) == (ln >> 3));
        #pragma unroll
        for (int nt = 0; nt < 4; ++nt) {
            short8 fa = mk8(pk(accK[nt][0],  accK[nt][1]),  pk(accK[nt][2],  accK[nt][3]),  0, 0);
            short8 fb = mk8(pk(accSl[nt][0], accSl[nt][1]), pk(accSl[nt][2], accSl[nt][3]), 0, 0);
            floatx4 L = MFMA16(fa, fb, z);
            float lg[4];
            #pragma unroll
            for (int i = 0; i < 4; ++i) {
                const bool valid = sameb && (4 * lq + i != ln);
                lg[i] = valid ? L[i] * 0.25f : -1e9f;   // 1/sqrt(16), exclude self/x-batch
            }
            float m = fmaxf(fmaxf(lg[0], lg[1]), fmaxf(lg[2], lg[3]));
            m = fmaxf(m, __shfl_xor(m, 16, 64));
            m = fmaxf(m, __shfl_xor(m, 32, 64));
            float e0 = __expf(lg[0] - m), e1 = __expf(lg[1] - m);
            float e2 = __expf(lg[2] - m), e3 = __expf(lg[3] - m);
            float ss = e0 + e1 + e2 + e3;
            ss += __shfl_xor(ss, 16, 64);
            ss += __shfl_xor(ss, 32, 64);
            const float inv = 1.f / ss;
            short8 fp = mk8(pk(e0 * inv, e1 * inv), pk(e2 * inv, e3 * inv), 0, 0);
            short8 fv = mk8(pV[nt][0], pV[nt][1], 0, 0);
            floatx4 O = MFMA16(fv, fp, z);
            pO[nt][0] = pk(O[0], O[1]);
            pO[nt][1] = pk(O[2], O[3]);
        }

        // ======== Phase 4: h = relu([E|other]@W1+b1) ; q = h@W2 + b2 ========
        short8 fO[2] = { mk8(pO[0][0], pO[0][1], pO[1][0], pO[1][1]),
                         mk8(pO[2][0], pO[2][1], pO[3][0], pO[3][1]) };
        floatx4 accH[4] = {z, z, z, z};
        #pragma unroll
        for (int s = 0; s < 4; ++s) {
            const int kk = s * 32 + lq * 8;
            const short8 af = (s < 2) ? fE[s] : fO[s - 2];
            #pragma unroll
            for (int nt = 0; nt < 4; ++nt)
                accH[nt] = MFMA16(af, *reinterpret_cast<const short8*>(lW1 + (nt * 16 + ln) * 136 + kk), accH[nt]);
        }
        float p0 = 0.f, p1 = 0.f, p2 = 0.f, p3 = 0.f;
        #pragma unroll
        for (int nt = 0; nt < 4; ++nt) {
            p0 += fmaxf(accH[nt][0] + b14[nt], 0.f) * w24[nt];
            p1 += fmaxf(accH[nt][1] + b14[nt], 0.f) * w24[nt];
            p2 += fmaxf(accH[nt][2] + b14[nt], 0.f) * w24[nt];
            p3 += fmaxf(accH[nt][3] + b14[nt], 0.f) * w24[nt];
        }
        #pragma unroll
        for (int mk = 1; mk < 16; mk <<= 1) {
            p0 += __shfl_xor(p0, mk, 64);
            p1 += __shfl_xor(p1, mk, 64);
            p2 += __shfl_xor(p2, mk, 64);
            p3 += __shfl_xor(p3, mk, 64);
        }
        if (ln == 0) {
            float pr[4] = {p0, p1, p2, p3};
            #pragma unroll
            for (int i = 0; i < 4; ++i) {
                const int slot = lq * 4 + i;           // slot -> (a = slot&7, bl = slot>>3)
                out[(long)(slot & 7) * B_N + b0 + wv * 2 + (slot >> 3)] = pr[i] + b2v;
            }
        }
        // no barriers: everything wave/lane-local; waves free-run across tiles
    }
}

extern "C" void kernel_launch(void* const* d_in, const int* in_sizes, int n_in,
                              void* d_out, int out_size, void* d_ws, size_t ws_size,
                              hipStream_t stream) {
    const float* states  = (const float*)d_in[0];
    const float* actions = (const float*)d_in[1];
    const float* Ws      = (const float*)d_in[2];
    const float* bs      = (const float*)d_in[3];
    const float* We      = (const float*)d_in[4];
    const float* be      = (const float*)d_in[5];
    const float* Wk      = (const float*)d_in[6];
    const float* Wsel    = (const float*)d_in[7];
    const float* Wv      = (const float*)d_in[8];
    const float* bv      = (const float*)d_in[9];
    const float* W1      = (const float*)d_in[10];
    const float* b1      = (const float*)d_in[11];
    const float* W2      = (const float*)d_in[12];
    const float* b2      = (const float*)d_in[13];
    short* wts = (short*)d_ws;
    float* out = (float*)d_out;

    prep_weights<<<(W_TOTAL + 255) / 256, 256, 0, stream>>>(Ws, bs, We, be, Wk, Wsel, Wv, W1, wts);
    attention_critic_mfma<<<B_N / (TILES * 16), 512, 0, stream>>>(
        states, actions, bv, b1, W2, b2, wts, out);
}

// Round 4
// 234.350 us; speedup vs baseline: 2.6241x; 1.4974x over previous
//
#include <hip/hip_runtime.h>
#include <hip/hip_bf16.h>

// A=8, B=32768, S=128, AD=16, H=64, NH=4, D=16
#define A_N 8
#define B_N 32768
#define S_N 128
#define AD_N 16

typedef __attribute__((ext_vector_type(8))) short short8;
typedef __attribute__((ext_vector_type(4))) float floatx4;
typedef __attribute__((ext_vector_type(4))) int intx4;

#define MFMA16(a, b, c) __builtin_amdgcn_mfma_f32_16x16x32_bf16(a, b, c, 0, 0, 0)
#define SBAR() __builtin_amdgcn_sched_barrier(0)

__device__ __forceinline__ short f2bf(float f) {
    __hip_bfloat16 h = __float2bfloat16(f);
    return *reinterpret_cast<short*>(&h);
}
// pack 2 f32 -> u32 of 2 bf16 (low short = first arg)
__device__ __forceinline__ int pk(float a, float b) {
    __hip_bfloat162 p = __float22bfloat162_rn(make_float2(a, b));
    return *reinterpret_cast<int*>(&p);
}
__device__ __forceinline__ short8 mk8(int a, int b, int c, int d) {
    intx4 v = {a, b, c, d};
    return *reinterpret_cast<short8*>(&v);
}
__device__ __forceinline__ void pk2(short8& r, int i, float a, float b) {
    __hip_bfloat162 p = __float22bfloat162_rn(make_float2(a, b));
    short2 s = *reinterpret_cast<short2*>(&p);
    r[i] = s.x; r[i + 1] = s.y;
}
__device__ __forceinline__ short8 cvt8(float4 x0, float4 x1) {
    short8 r;
    pk2(r, 0, x0.x, x0.y); pk2(r, 2, x0.z, x0.w);
    pk2(r, 4, x1.x, x1.y); pk2(r, 6, x1.z, x1.w);
    return r;
}

// k-permutation for the phase-2/4 weight operands: physical LDS position p
// (p = s*32 + lq*8 + t) holds logical channel ch = 32s + 16(t>>2) + 4lq + (t&3).
// This makes the activation-side fragment a pure within-lane repack of the
// previous MFMA's accumulator (lane (lq,ln) holds channels nt*16+4lq+i).
__device__ __forceinline__ int chperm(int p) {
    return 32 * (p >> 5) + 16 * ((p & 7) >> 2) + 4 * ((p >> 3) & 3) + (p & 3);
}

// ---- weight prep into d_ws: bf16 [n][k] rows, bank-spread strides ----
// shorts: lWe[64][168]@0 (identity k; k=144 holds be) | lWs[64][168]@10752 (k=144 holds bs)
//         lWk[64][72]@21504 | lWsel[64][72]@26112 | lWv[64][72]@30720 (chperm k)
//         lW1[64][136]@35328 (chperm k)
#define OFF_Ws   10752
#define OFF_Wk   21504
#define OFF_Wsel 26112
#define OFF_Wv   30720
#define OFF_W1   35328
#define W_TOTAL  44032   // shorts = 88064 B = 86 x 1 KiB chunks

__global__ void prep_weights(const float* __restrict__ Ws, const float* __restrict__ bs,
                             const float* __restrict__ We, const float* __restrict__ be,
                             const float* __restrict__ Wk, const float* __restrict__ Wsel,
                             const float* __restrict__ Wv, const float* __restrict__ W1,
                             short* __restrict__ w) {
    int idx = blockIdx.x * 256 + threadIdx.x;
    if (idx >= W_TOTAL) return;
    float v = 0.f;
    if (idx < OFF_Ws) {
        int n = idx / 168, p = idx % 168;
        v = (p < 144) ? We[p * 64 + n] : (p == 144 ? be[n] : 0.f);
    } else if (idx < OFF_Wk) {
        int i = idx - OFF_Ws; int n = i / 168, p = i % 168;
        v = (p < 128) ? Ws[p * 64 + n] : (p == 144 ? bs[n] : 0.f);
    } else if (idx < OFF_Wsel) {
        int i = idx - OFF_Wk; int n = i / 72, p = i % 72;
        if (p < 64) v = Wk[(n >> 4) * 1024 + chperm(p) * 16 + (n & 15)];
    } else if (idx < OFF_Wv) {
        int i = idx - OFF_Wsel; int n = i / 72, p = i % 72;
        if (p < 64) v = Wsel[(n >> 4) * 1024 + chperm(p) * 16 + (n & 15)];
    } else if (idx < OFF_W1) {
        int i = idx - OFF_Wv; int n = i / 72, p = i % 72;
        if (p < 64) v = Wv[(n >> 4) * 1024 + chperm(p) * 16 + (n & 15)];
    } else {
        int i = idx - OFF_W1; int n = i / 136, p = i % 136;
        if (p < 128) v = W1[chperm(p) * 64 + n];
    }
    w[idx] = f2bf(v);
}

#define TILES 8   // 16 batches/tile/block, 128 batches/block, grid = 256 = #CUs

// Register-resident pipeline, v4 (pressure-shaped): the gfx950 backend splits
// the unified 256-reg budget ~50/50 arch/AGPR when MFMA accumulators land in
// AGPRs, so the real arch budget is ~128. v3 spilled (~21 regs/tile-iter,
// ~370 MB scratch traffic) because the scheduler merged phases into one region
// whose operand-prefetch + dual accumulator sets peaked ~150 arch regs.
// v4: narrow passes (E then S; K/Sel then V; pack accumulators to bf16 ints
// at each pass end) + sched_barrier(0) fences between passes so the scheduler
// cannot re-merge them. Per-pass arch peak ~70-85 << 128 -> no spill.
// Wave wv owns 16 slots = 2 batches x 8 agents; slot s: a=s&7, bl=s>>3.
__global__ __launch_bounds__(512, 2)
void attention_critic_mfma(
    const float* __restrict__ states, const float* __restrict__ actions,
    const float* __restrict__ bv, const float* __restrict__ b1,
    const float* __restrict__ W2, const float* __restrict__ b2,
    const short* __restrict__ wts, float* __restrict__ out)
{
    __shared__ __align__(16) short smem[W_TOTAL];
    const short* lWe   = smem;
    const short* lWs   = smem + OFF_Ws;
    const short* lWk   = smem + OFF_Wk;
    const short* lWsel = smem + OFF_Wsel;
    const short* lWv   = smem + OFF_Wv;
    const short* lW1   = smem + OFF_W1;

    const int tid  = threadIdx.x;
    const int wv   = tid >> 6;       // wave 0..7
    const int lane = tid & 63;
    const int lq   = lane >> 4;
    const int ln   = lane & 15;

    // ---- stage all weights into LDS (86 x 1KiB chunks, global_load_lds w=16) ----
    for (int c = wv; c < 86; c += 8) {
        const unsigned int* g = reinterpret_cast<const unsigned int*>(wts + c * 512) + lane * 4;
        __builtin_amdgcn_global_load_lds(g, reinterpret_cast<unsigned int*>(smem + c * 512), 16, 0, 0);
    }

    // per-lane bias / head-weight constants (cols of the respective C-layouts)
    float bv4[4], b14[4], w24[4];
    #pragma unroll
    for (int nt = 0; nt < 4; ++nt) {
        bv4[nt] = bv[nt * 16 + ln];
        b14[nt] = b1[nt * 16 + ln];
        w24[nt] = W2[nt * 16 + ln];
    }
    const float b2v = b2[0];

    const int bbase = blockIdx.x * (TILES * 16);
    const int aA  = ln & 7;
    const int blA = ln >> 3;
    const float* srow = states  + ((long)aA * B_N + bbase + wv * 2 + blA) * S_N;
    const float* arow = actions + ((long)aA * B_N + bbase + wv * 2 + blA) * AD_N;

    __syncthreads();   // weights staged (drains vmcnt incl. global_load_lds)

    const floatx4 z  = {0.f, 0.f, 0.f, 0.f};
    const short8  z8 = {0, 0, 0, 0, 0, 0, 0, 0};

    #pragma unroll 1
    for (int t = 0; t < TILES; ++t) {
        const int b0 = bbase + t * 16;

        // ---- load + convert this tile's inputs (transient f32, 20-reg xf) ----
        short8 xf[5];
        #pragma unroll
        for (int s = 0; s < 4; ++s) {
            float4 f0 = *reinterpret_cast<const float4*>(srow + s * 32 + lq * 8);
            float4 f1 = *reinterpret_cast<const float4*>(srow + s * 32 + lq * 8 + 4);
            xf[s] = cvt8(f0, f1);
        }
        {
            short8 xt = z8;
            if (lq < 2) {
                float4 f0 = *reinterpret_cast<const float4*>(arow + lq * 8);
                float4 f1 = *reinterpret_cast<const float4*>(arow + lq * 8 + 4);
                xt = cvt8(f0, f1);
            } else if (lq == 2) {
                xt[0] = (short)0x3F80;   // bf16(1.0) at k=144 -> bias row
            }
            xf[4] = xt;
        }
        srow += 16 * S_N; arow += 16 * AD_N;

        // ======== Phase 1a: E^T = We^T@X^T (swapped), relu, pack ========
        short8 fE[2];
        {
            floatx4 accE[4] = {z, z, z, z};
            #pragma unroll
            for (int s = 0; s < 5; ++s) {
                const int kk = s * 32 + lq * 8;
                #pragma unroll
                for (int nt = 0; nt < 4; ++nt)
                    accE[nt] = MFMA16(*reinterpret_cast<const short8*>(lWe + (nt * 16 + ln) * 168 + kk), xf[s], accE[nt]);
            }
            int pE[4][2];
            #pragma unroll
            for (int nt = 0; nt < 4; ++nt) {
                pE[nt][0] = pk(fmaxf(accE[nt][0], 0.f), fmaxf(accE[nt][1], 0.f));
                pE[nt][1] = pk(fmaxf(accE[nt][2], 0.f), fmaxf(accE[nt][3], 0.f));
            }
            fE[0] = mk8(pE[0][0], pE[0][1], pE[1][0], pE[1][1]);
            fE[1] = mk8(pE[2][0], pE[2][1], pE[3][0], pE[3][1]);
        }
        SBAR();

        // ======== Phase 1b: S^T = Ws^T@X^T (k<=128 + bias row), relu, pack ====
        short8 fS[2];
        {
            floatx4 accS[4] = {z, z, z, z};
            #pragma unroll
            for (int s = 0; s < 5; ++s) {
                if (s == 4 && lq != 2) {
                    // only the bias row (k=144, lq==2) contributes in the tail;
                    // still issue uniformly to keep exec simple: xf[4] is zero
                    // for lq==3 and actions for lq<2, but lWs rows are zero for
                    // 128<=k<144 and k>144, so all tail products are exact.
                }
                const int kk = s * 32 + lq * 8;
                #pragma unroll
                for (int nt = 0; nt < 4; ++nt)
                    accS[nt] = MFMA16(*reinterpret_cast<const short8*>(lWs + (nt * 16 + ln) * 168 + kk), xf[s], accS[nt]);
            }
            int pS[4][2];
            #pragma unroll
            for (int nt = 0; nt < 4; ++nt) {
                pS[nt][0] = pk(fmaxf(accS[nt][0], 0.f), fmaxf(accS[nt][1], 0.f));
                pS[nt][1] = pk(fmaxf(accS[nt][2], 0.f), fmaxf(accS[nt][3], 0.f));
            }
            fS[0] = mk8(pS[0][0], pS[0][1], pS[1][0], pS[1][1]);
            fS[1] = mk8(pS[2][0], pS[2][1], pS[3][0], pS[3][1]);
        }
        SBAR();

        // ======== Phase 2a: K^T = Wk^T@E, Sel^T = Wsel^T@S; pack per head ====
        int kp[4][2], sp[4][2];
        {
            floatx4 accK[4] = {z, z, z, z}, accSl[4] = {z, z, z, z};
            #pragma unroll
            for (int s = 0; s < 2; ++s) {
                const int kk = s * 32 + lq * 8;
                #pragma unroll
                for (int nt = 0; nt < 4; ++nt) {
                    const int rw = (nt * 16 + ln);
                    accK[nt]  = MFMA16(*reinterpret_cast<const short8*>(lWk   + rw * 72 + kk), fE[s], accK[nt]);
                    accSl[nt] = MFMA16(*reinterpret_cast<const short8*>(lWsel + rw * 72 + kk), fS[s], accSl[nt]);
                }
            }
            #pragma unroll
            for (int nt = 0; nt < 4; ++nt) {
                kp[nt][0] = pk(accK[nt][0],  accK[nt][1]);
                kp[nt][1] = pk(accK[nt][2],  accK[nt][3]);
                sp[nt][0] = pk(accSl[nt][0], accSl[nt][1]);
                sp[nt][1] = pk(accSl[nt][2], accSl[nt][3]);
            }
        }
        SBAR();

        // ======== Phase 2b: V = relu(E@Wv + bv); pack ========
        int pV[4][2];
        {
            floatx4 accV[4] = {z, z, z, z};
            #pragma unroll
            for (int s = 0; s < 2; ++s) {
                const int kk = s * 32 + lq * 8;
                #pragma unroll
                for (int nt = 0; nt < 4; ++nt)
                    accV[nt] = MFMA16(fE[s], *reinterpret_cast<const short8*>(lWv + (nt * 16 + ln) * 72 + kk), accV[nt]);
            }
            #pragma unroll
            for (int nt = 0; nt < 4; ++nt) {
                pV[nt][0] = pk(fmaxf(accV[nt][0] + bv4[nt], 0.f), fmaxf(accV[nt][1] + bv4[nt], 0.f));
                pV[nt][1] = pk(fmaxf(accV[nt][2] + bv4[nt], 0.f), fmaxf(accV[nt][3] + bv4[nt], 0.f));
            }
        }
        SBAR();

        // ======== Phase 3: attention, fully in-register ========
        // L-MFMA (K=32, upper half zero): A = own-slot K (rows=j-slot=ln),
        // B = own-slot Sel (cols=i-slot=ln) -> L[j=4lq+i][i=ln].
        // Softmax over j = 4 regs + shfl_xor(16,32). PV-MFMA: A = V (rows=d=ln),
        // B = P -> other^T[d=4lq+i][slot=ln]. Cross-batch/self masked in P.
        int pO[4][2];
        {
            const bool sameb = ((lq >> 1) == (ln >> 3));
            #pragma unroll
            for (int nt = 0; nt < 4; ++nt) {
                short8 fa = mk8(kp[nt][0], kp[nt][1], 0, 0);
                short8 fb = mk8(sp[nt][0], sp[nt][1], 0, 0);
                floatx4 L = MFMA16(fa, fb, z);
                float lg[4];
                #pragma unroll
                for (int i = 0; i < 4; ++i) {
                    const bool valid = sameb && (4 * lq + i != ln);
                    lg[i] = valid ? L[i] * 0.25f : -1e9f;   // 1/sqrt(16), excl self/x-batch
                }
                float m = fmaxf(fmaxf(lg[0], lg[1]), fmaxf(lg[2], lg[3]));
                m = fmaxf(m, __shfl_xor(m, 16, 64));
                m = fmaxf(m, __shfl_xor(m, 32, 64));
                float e0 = __expf(lg[0] - m), e1 = __expf(lg[1] - m);
                float e2 = __expf(lg[2] - m), e3 = __expf(lg[3] - m);
                float ss = e0 + e1 + e2 + e3;
                ss += __shfl_xor(ss, 16, 64);
                ss += __shfl_xor(ss, 32, 64);
                const float inv = 1.f / ss;
                short8 fp = mk8(pk(e0 * inv, e1 * inv), pk(e2 * inv, e3 * inv), 0, 0);
                short8 fv = mk8(pV[nt][0], pV[nt][1], 0, 0);
                floatx4 O = MFMA16(fv, fp, z);
                pO[nt][0] = pk(O[0], O[1]);
                pO[nt][1] = pk(O[2], O[3]);
            }
        }
        SBAR();

        // ======== Phase 4: h = relu([E|other]@W1+b1) ; q = h@W2 + b2 ========
        {
            short8 fO[2] = { mk8(pO[0][0], pO[0][1], pO[1][0], pO[1][1]),
                             mk8(pO[2][0], pO[2][1], pO[3][0], pO[3][1]) };
            floatx4 accH[4] = {z, z, z, z};
            #pragma unroll
            for (int s = 0; s < 4; ++s) {
                const int kk = s * 32 + lq * 8;
                const short8 af = (s < 2) ? fE[s] : fO[s - 2];
                #pragma unroll
                for (int nt = 0; nt < 4; ++nt)
                    accH[nt] = MFMA16(af, *reinterpret_cast<const short8*>(lW1 + (nt * 16 + ln) * 136 + kk), accH[nt]);
            }
            float p0 = 0.f, p1 = 0.f, p2 = 0.f, p3 = 0.f;
            #pragma unroll
            for (int nt = 0; nt < 4; ++nt) {
                p0 += fmaxf(accH[nt][0] + b14[nt], 0.f) * w24[nt];
                p1 += fmaxf(accH[nt][1] + b14[nt], 0.f) * w24[nt];
                p2 += fmaxf(accH[nt][2] + b14[nt], 0.f) * w24[nt];
                p3 += fmaxf(accH[nt][3] + b14[nt], 0.f) * w24[nt];
            }
            #pragma unroll
            for (int mk = 1; mk < 16; mk <<= 1) {
                p0 += __shfl_xor(p0, mk, 64);
                p1 += __shfl_xor(p1, mk, 64);
                p2 += __shfl_xor(p2, mk, 64);
                p3 += __shfl_xor(p3, mk, 64);
            }
            if (ln == 0) {
                float pr[4] = {p0, p1, p2, p3};
                #pragma unroll
                for (int i = 0; i < 4; ++i) {
                    const int slot = lq * 4 + i;       // slot -> (a = slot&7, bl = slot>>3)
                    out[(long)(slot & 7) * B_N + b0 + wv * 2 + (slot >> 3)] = pr[i] + b2v;
                }
            }
        }
        SBAR();   // keep next tile's loads/compute out of this region
        // no barriers: everything wave/lane-local; waves free-run across tiles
    }
}

extern "C" void kernel_launch(void* const* d_in, const int* in_sizes, int n_in,
                              void* d_out, int out_size, void* d_ws, size_t ws_size,
                              hipStream_t stream) {
    const float* states  = (const float*)d_in[0];
    const float* actions = (const float*)d_in[1];
    const float* Ws      = (const float*)d_in[2];
    const float* bs      = (const float*)d_in[3];
    const float* We      = (const float*)d_in[4];
    const float* be      = (const float*)d_in[5];
    const float* Wk      = (const float*)d_in[6];
    const float* Wsel    = (const float*)d_in[7];
    const float* Wv      = (const float*)d_in[8];
    const float* bv      = (const float*)d_in[9];
    const float* W1      = (const float*)d_in[10];
    const float* b1      = (const float*)d_in[11];
    const float* W2      = (const float*)d_in[12];
    const float* b2      = (const float*)d_in[13];
    short* wts = (short*)d_ws;
    float* out = (float*)d_out;

    prep_weights<<<(W_TOTAL + 255) / 256, 256, 0, stream>>>(Ws, bs, We, be, Wk, Wsel, Wv, W1, wts);
    attention_critic_mfma<<<B_N / (TILES * 16), 512, 0, stream>>>(
        states, actions, bv, b1, W2, b2, wts, out);
}

// Round 5
// 234.317 us; speedup vs baseline: 2.6245x; 1.0001x over previous
//
#include <hip/hip_runtime.h>
#include <hip/hip_bf16.h>

// A=8, B=32768, S=128, AD=16, H=64, NH=4, D=16
#define A_N 8
#define B_N 32768
#define S_N 128
#define AD_N 16

typedef __attribute__((ext_vector_type(8))) short short8;
typedef __attribute__((ext_vector_type(4))) float floatx4;
typedef __attribute__((ext_vector_type(4))) int intx4;

#define MFMA16(a, b, c) __builtin_amdgcn_mfma_f32_16x16x32_bf16(a, b, c, 0, 0, 0)
#define SBAR() __builtin_amdgcn_sched_barrier(0)

__device__ __forceinline__ short f2bf(float f) {
    __hip_bfloat16 h = __float2bfloat16(f);
    return *reinterpret_cast<short*>(&h);
}
// pack 2 f32 -> u32 of 2 bf16 (low short = first arg)
__device__ __forceinline__ int pk(float a, float b) {
    __hip_bfloat162 p = __float22bfloat162_rn(make_float2(a, b));
    return *reinterpret_cast<int*>(&p);
}
__device__ __forceinline__ short8 mk8(int a, int b, int c, int d) {
    intx4 v = {a, b, c, d};
    return *reinterpret_cast<short8*>(&v);
}
__device__ __forceinline__ void pk2(short8& r, int i, float a, float b) {
    __hip_bfloat162 p = __float22bfloat162_rn(make_float2(a, b));
    short2 s = *reinterpret_cast<short2*>(&p);
    r[i] = s.x; r[i + 1] = s.y;
}
__device__ __forceinline__ short8 cvt8(float4 x0, float4 x1) {
    short8 r;
    pk2(r, 0, x0.x, x0.y); pk2(r, 2, x0.z, x0.w);
    pk2(r, 4, x1.x, x1.y); pk2(r, 6, x1.z, x1.w);
    return r;
}

// k-permutation for the phase-2/4 weight operands: physical k position p
// (p = s*32 + lq*8 + e) holds logical channel ch = 32s + 16(e>>2) + 4lq + (e&3),
// so the activation-side fragment is a pure within-lane repack of the previous
// MFMA's accumulator (lane (lq,ln) holds channels nt*16+4lq+i).
__device__ __forceinline__ int chperm(int p) {
    return 32 * (p >> 5) + 16 * ((p & 7) >> 2) + 4 * ((p >> 3) & 3) + (p & 3);
}

// ---- weight prep into d_ws: FRAGMENT-MAJOR bf16 ----
// Each 16B MFMA weight fragment (s, lq, ch) stored contiguously at short
// offset ((s*4+lq)*64 + ch)*8, element e = W[perm(s*32+lq*8+e)][ch].
// -> zero padding (76 KB total, fits 2 blocks/CU), conflict-free (each
// 16-lane quarter reads a contiguous 256B run), and in-kernel addressing is
// one base VGPR + compile-time immediates.
// shorts: We[K=160]@0 (k identity; k=144 holds be) | Ws[K=128]@10240 (bias via VALU)
//         Wk[K=64]@18432 | Wsel@22528 | Wv@26624 (chperm) | W1[K=128]@30720 (chperm)
#define OFF_Ws   10240
#define OFF_Wk   18432
#define OFF_Wsel 22528
#define OFF_Wv   26624
#define OFF_W1   30720
#define W_TOTAL  38912   // shorts = 77824 B = 76 x 1 KiB chunks

__global__ void prep_weights(const float* __restrict__ Ws, const float* __restrict__ We,
                             const float* __restrict__ be,
                             const float* __restrict__ Wk, const float* __restrict__ Wsel,
                             const float* __restrict__ Wv, const float* __restrict__ W1,
                             short* __restrict__ w) {
    int idx = blockIdx.x * 256 + threadIdx.x;
    if (idx >= W_TOTAL) return;
    float v = 0.f;
    int i, base;
    if (idx < OFF_Ws)        { i = idx;            base = 0; }
    else if (idx < OFF_Wk)   { i = idx - OFF_Ws;   base = 1; }
    else if (idx < OFF_Wsel) { i = idx - OFF_Wk;   base = 2; }
    else if (idx < OFF_Wv)   { i = idx - OFF_Wsel; base = 3; }
    else if (idx < OFF_W1)   { i = idx - OFF_Wv;   base = 4; }
    else                     { i = idx - OFF_W1;   base = 5; }
    const int e   = i & 7;
    const int f   = i >> 3;
    const int ch  = f & 63;
    const int slq = f >> 6;
    const int p   = (slq >> 2) * 32 + (slq & 3) * 8 + e;
    if (base == 0)      v = (p < 144) ? We[p * 64 + ch] : (p == 144 ? be[ch] : 0.f);
    else if (base == 1) v = Ws[p * 64 + ch];
    else if (base == 2) v = Wk[(ch >> 4) * 1024 + chperm(p) * 16 + (ch & 15)];
    else if (base == 3) v = Wsel[(ch >> 4) * 1024 + chperm(p) * 16 + (ch & 15)];
    else if (base == 4) v = Wv[(ch >> 4) * 1024 + chperm(p) * 16 + (ch & 15)];
    else                v = W1[chperm(p) * 64 + ch];
    w[idx] = f2bf(v);
}

#define TILES 4   // 16 batches/tile/block, 64 batches/block, grid = 512 = 2 blocks/CU

// v5: occupancy doubling. LDS shrunk to 76 KB (fragment-major, no padding) and
// __launch_bounds__(512,4) caps unified VGPR at 128/wave -> 2 blocks (16 waves)
// per CU. Narrow pressure-shaped passes (v4) keep the per-phase live-set
// ~116 unified so the 128 cap fits without scratch spill. All weight ds_reads
// are base+immediate (fragment-major), conflict-free by construction.
// Wave wv owns 16 slots = 2 batches x 8 agents; slot s: a=s&7, bl=s>>3.
__global__ __launch_bounds__(512, 4)
void attention_critic_mfma(
    const float* __restrict__ states, const float* __restrict__ actions,
    const float* __restrict__ bs, const float* __restrict__ bv,
    const float* __restrict__ b1, const float* __restrict__ W2,
    const float* __restrict__ b2,
    const short* __restrict__ wts, float* __restrict__ out)
{
    __shared__ __align__(16) short smem[W_TOTAL];

    const int tid  = threadIdx.x;
    const int wv   = tid >> 6;       // wave 0..7
    const int lane = tid & 63;
    const int lq   = lane >> 4;
    const int ln   = lane & 15;

    // ---- stage all weights into LDS (76 x 1KiB chunks, global_load_lds w=16) ----
    for (int c = wv; c < 76; c += 8) {
        const unsigned int* g = reinterpret_cast<const unsigned int*>(wts + c * 512) + lane * 4;
        __builtin_amdgcn_global_load_lds(g, reinterpret_cast<unsigned int*>(smem + c * 512), 16, 0, 0);
    }

    // fragment-major per-lane base: fragment (s,lq,ch=nt*16+ln) lives at
    // short offset OFF + s*2048 + nt*128 + (lq*512 + ln*8)
    const int lo = lq * 512 + ln * 8;
    const short* lbA = smem + lo;             // We/Ws/Wk/Wsel (byte offs < 64K)
    const short* lbB = smem + OFF_Wv + lo;    // Wv/W1

    // per-lane bias / head-weight constants (cols of the respective C-layouts)
    float bS4[4], bv4[4], b14[4], w24[4];
    #pragma unroll
    for (int nt = 0; nt < 4; ++nt) {
        bS4[nt] = bs[nt * 16 + ln];
        bv4[nt] = bv[nt * 16 + ln];
        b14[nt] = b1[nt * 16 + ln];
        w24[nt] = W2[nt * 16 + ln];
    }
    const float b2v = b2[0];

    const int bbase = blockIdx.x * (TILES * 16);
    const int aA  = ln & 7;
    const int blA = ln >> 3;
    const float* srow = states  + ((long)aA * B_N + bbase + wv * 2 + blA) * S_N;
    const float* arow = actions + ((long)aA * B_N + bbase + wv * 2 + blA) * AD_N;

    __syncthreads();   // weights staged (drains vmcnt incl. global_load_lds)

    const floatx4 z = {0.f, 0.f, 0.f, 0.f};

    #pragma unroll 1
    for (int t = 0; t < TILES; ++t) {
        const int b0 = bbase + t * 16;

        // ---- load + convert this tile's inputs (transient f32, 20-reg xf) ----
        short8 xf[5];
        #pragma unroll
        for (int s = 0; s < 4; ++s) {
            float4 f0 = *reinterpret_cast<const float4*>(srow + s * 32 + lq * 8);
            float4 f1 = *reinterpret_cast<const float4*>(srow + s * 32 + lq * 8 + 4);
            xf[s] = cvt8(f0, f1);
        }
        {
            short8 xt = {0, 0, 0, 0, 0, 0, 0, 0};
            if (lq < 2) {
                float4 f0 = *reinterpret_cast<const float4*>(arow + lq * 8);
                float4 f1 = *reinterpret_cast<const float4*>(arow + lq * 8 + 4);
                xt = cvt8(f0, f1);
            } else if (lq == 2) {
                xt[0] = (short)0x3F80;   // bf16(1.0) at k=144 -> be bias row
            }
            xf[4] = xt;
        }
        srow += 16 * S_N; arow += 16 * AD_N;

        // ======== Phase 1a: E^T = We^T@X^T (swapped), relu, pack ========
        short8 fE[2];
        {
            floatx4 accE[4] = {z, z, z, z};
            #pragma unroll
            for (int s = 0; s < 5; ++s)
                #pragma unroll
                for (int nt = 0; nt < 4; ++nt)
                    accE[nt] = MFMA16(*reinterpret_cast<const short8*>(lbA + s * 2048 + nt * 128), xf[s], accE[nt]);
            int pE[4][2];
            #pragma unroll
            for (int nt = 0; nt < 4; ++nt) {
                pE[nt][0] = pk(fmaxf(accE[nt][0], 0.f), fmaxf(accE[nt][1], 0.f));
                pE[nt][1] = pk(fmaxf(accE[nt][2], 0.f), fmaxf(accE[nt][3], 0.f));
            }
            fE[0] = mk8(pE[0][0], pE[0][1], pE[1][0], pE[1][1]);
            fE[1] = mk8(pE[2][0], pE[2][1], pE[3][0], pE[3][1]);
        }
        SBAR();

        // ======== Phase 1b: S^T = Ws^T@X^T (K=128), +bs via VALU, relu, pack ==
        short8 fS[2];
        {
            floatx4 accS[4] = {z, z, z, z};
            #pragma unroll
            for (int s = 0; s < 4; ++s)
                #pragma unroll
                for (int nt = 0; nt < 4; ++nt)
                    accS[nt] = MFMA16(*reinterpret_cast<const short8*>(lbA + OFF_Ws + s * 2048 + nt * 128), xf[s], accS[nt]);
            int pS[4][2];
            #pragma unroll
            for (int nt = 0; nt < 4; ++nt) {
                pS[nt][0] = pk(fmaxf(accS[nt][0] + bS4[nt], 0.f), fmaxf(accS[nt][1] + bS4[nt], 0.f));
                pS[nt][1] = pk(fmaxf(accS[nt][2] + bS4[nt], 0.f), fmaxf(accS[nt][3] + bS4[nt], 0.f));
            }
            fS[0] = mk8(pS[0][0], pS[0][1], pS[1][0], pS[1][1]);
            fS[1] = mk8(pS[2][0], pS[2][1], pS[3][0], pS[3][1]);
        }
        SBAR();

        // ======== Phase 2a: K^T = Wk^T@E, Sel^T = Wsel^T@S; pack per head ====
        int kp[4][2], sp[4][2];
        {
            floatx4 accK[4] = {z, z, z, z}, accSl[4] = {z, z, z, z};
            #pragma unroll
            for (int s = 0; s < 2; ++s)
                #pragma unroll
                for (int nt = 0; nt < 4; ++nt) {
                    accK[nt]  = MFMA16(*reinterpret_cast<const short8*>(lbA + OFF_Wk   + s * 2048 + nt * 128), fE[s], accK[nt]);
                    accSl[nt] = MFMA16(*reinterpret_cast<const short8*>(lbA + OFF_Wsel + s * 2048 + nt * 128), fS[s], accSl[nt]);
                }
            #pragma unroll
            for (int nt = 0; nt < 4; ++nt) {
                kp[nt][0] = pk(accK[nt][0],  accK[nt][1]);
                kp[nt][1] = pk(accK[nt][2],  accK[nt][3]);
                sp[nt][0] = pk(accSl[nt][0], accSl[nt][1]);
                sp[nt][1] = pk(accSl[nt][2], accSl[nt][3]);
            }
        }
        SBAR();

        // ======== Phase 2b: V = relu(E@Wv + bv); pack ========
        int pV[4][2];
        {
            floatx4 accV[4] = {z, z, z, z};
            #pragma unroll
            for (int s = 0; s < 2; ++s)
                #pragma unroll
                for (int nt = 0; nt < 4; ++nt)
                    accV[nt] = MFMA16(fE[s], *reinterpret_cast<const short8*>(lbB + s * 2048 + nt * 128), accV[nt]);
            #pragma unroll
            for (int nt = 0; nt < 4; ++nt) {
                pV[nt][0] = pk(fmaxf(accV[nt][0] + bv4[nt], 0.f), fmaxf(accV[nt][1] + bv4[nt], 0.f));
                pV[nt][1] = pk(fmaxf(accV[nt][2] + bv4[nt], 0.f), fmaxf(accV[nt][3] + bv4[nt], 0.f));
            }
        }
        SBAR();

        // ======== Phase 3: attention, fully in-register ========
        // L-MFMA (K=32, upper half zero): A = own-slot K (rows=j-slot=ln),
        // B = own-slot Sel (cols=i-slot=ln) -> L[j=4lq+i][i=ln].
        // Softmax over j = 4 regs + shfl_xor(16,32). PV-MFMA: A = V (rows=d=ln),
        // B = P -> other^T[d=4lq+i][slot=ln]. Cross-batch/self masked in P.
        int pO[4][2];
        {
            const bool sameb = ((lq >> 1) == (ln >> 3));
            #pragma unroll
            for (int nt = 0; nt < 4; ++nt) {
                short8 fa = mk8(kp[nt][0], kp[nt][1], 0, 0);
                short8 fb = mk8(sp[nt][0], sp[nt][1], 0, 0);
                floatx4 L = MFMA16(fa, fb, z);
                float lg[4];
                #pragma unroll
                for (int i = 0; i < 4; ++i) {
                    const bool valid = sameb && (4 * lq + i != ln);
                    lg[i] = valid ? L[i] * 0.25f : -1e9f;   // 1/sqrt(16), excl self/x-batch
                }
                float m = fmaxf(fmaxf(lg[0], lg[1]), fmaxf(lg[2], lg[3]));
                m = fmaxf(m, __shfl_xor(m, 16, 64));
                m = fmaxf(m, __shfl_xor(m, 32, 64));
                float e0 = __expf(lg[0] - m), e1 = __expf(lg[1] - m);
                float e2 = __expf(lg[2] - m), e3 = __expf(lg[3] - m);
                float ss = e0 + e1 + e2 + e3;
                ss += __shfl_xor(ss, 16, 64);
                ss += __shfl_xor(ss, 32, 64);
                const float inv = 1.f / ss;
                short8 fp = mk8(pk(e0 * inv, e1 * inv), pk(e2 * inv, e3 * inv), 0, 0);
                short8 fv = mk8(pV[nt][0], pV[nt][1], 0, 0);
                floatx4 O = MFMA16(fv, fp, z);
                pO[nt][0] = pk(O[0], O[1]);
                pO[nt][1] = pk(O[2], O[3]);
            }
        }
        SBAR();

        // ======== Phase 4: h = relu([E|other]@W1+b1) ; q = h@W2 + b2 ========
        {
            short8 fO[2] = { mk8(pO[0][0], pO[0][1], pO[1][0], pO[1][1]),
                             mk8(pO[2][0], pO[2][1], pO[3][0], pO[3][1]) };
            floatx4 accH[4] = {z, z, z, z};
            #pragma unroll
            for (int s = 0; s < 4; ++s) {
                const short8 af = (s < 2) ? fE[s] : fO[s - 2];
                #pragma unroll
                for (int nt = 0; nt < 4; ++nt)
                    accH[nt] = MFMA16(af, *reinterpret_cast<const short8*>(lbB + 4096 + s * 2048 + nt * 128), accH[nt]);
            }
            float p0 = 0.f, p1 = 0.f, p2 = 0.f, p3 = 0.f;
            #pragma unroll
            for (int nt = 0; nt < 4; ++nt) {
                p0 += fmaxf(accH[nt][0] + b14[nt], 0.f) * w24[nt];
                p1 += fmaxf(accH[nt][1] + b14[nt], 0.f) * w24[nt];
                p2 += fmaxf(accH[nt][2] + b14[nt], 0.f) * w24[nt];
                p3 += fmaxf(accH[nt][3] + b14[nt], 0.f) * w24[nt];
            }
            #pragma unroll
            for (int mk = 1; mk < 16; mk <<= 1) {
                p0 += __shfl_xor(p0, mk, 64);
                p1 += __shfl_xor(p1, mk, 64);
                p2 += __shfl_xor(p2, mk, 64);
                p3 += __shfl_xor(p3, mk, 64);
            }
            if (ln == 0) {
                float pr[4] = {p0, p1, p2, p3};
                #pragma unroll
                for (int i = 0; i < 4; ++i) {
                    const int slot = lq * 4 + i;       // slot -> (a = slot&7, bl = slot>>3)
                    out[(long)(slot & 7) * B_N + b0 + wv * 2 + (slot >> 3)] = pr[i] + b2v;
                }
            }
        }
        SBAR();   // keep next tile's loads/compute out of this region
        // no barriers in the loop: everything wave/lane-local; waves free-run
    }
}

extern "C" void kernel_launch(void* const* d_in, const int* in_sizes, int n_in,
                              void* d_out, int out_size, void* d_ws, size_t ws_size,
                              hipStream_t stream) {
    const float* states  = (const float*)d_in[0];
    const float* actions = (const float*)d_in[1];
    const float* Ws      = (const float*)d_in[2];
    const float* bs      = (const float*)d_in[3];
    const float* We      = (const float*)d_in[4];
    const float* be      = (const float*)d_in[5];
    const float* Wk      = (const float*)d_in[6];
    const float* Wsel    = (const float*)d_in[7];
    const float* Wv      = (const float*)d_in[8];
    const float* bv      = (const float*)d_in[9];
    const float* W1      = (const float*)d_in[10];
    const float* b1      = (const float*)d_in[11];
    const float* W2      = (const float*)d_in[12];
    const float* b2      = (const float*)d_in[13];
    short* wts = (short*)d_ws;
    float* out = (float*)d_out;

    prep_weights<<<(W_TOTAL + 255) / 256, 256, 0, stream>>>(Ws, We, be, Wk, Wsel, Wv, W1, wts);
    attention_critic_mfma<<<B_N / (TILES * 16), 512, 0, stream>>>(
        states, actions, bs, bv, b1, W2, b2, wts, out);
}